// Round 1
// baseline (87.329 us; speedup 1.0000x reference)
//
#include <hip/hip_runtime.h>
#include <hip/hip_bf16.h>
#include <math.h>

#define F_DIM 2048
#define B_DIM 4096
#define C_DIM 100
#define D_DIM 16
#define N_DIM (C_DIM*D_DIM)   // 1600
#define RIDGE_EPS 1e-4f

typedef __attribute__((ext_vector_type(8))) short bf16x8;
typedef __attribute__((ext_vector_type(4))) float f32x4;

__device__ __forceinline__ void gload16(const void* g, void* l) {
  __builtin_amdgcn_global_load_lds(
      (const __attribute__((address_space(1))) void*)g,
      (__attribute__((address_space(3))) void*)l,
      16, 0, 0);
}

// ---------------- fp32 -> bf16 (RNE) convert, 8 elems/thread ----------------
__global__ void cvt_bf16_kernel(const float* __restrict__ in,
                                unsigned short* __restrict__ outp, int n8) {
  int i = blockIdx.x * blockDim.x + threadIdx.x;
  if (i >= n8) return;
  const float4* p = (const float4*)in + (size_t)i * 2;
  float4 a = p[0], b = p[1];
  float v[8] = {a.x, a.y, a.z, a.w, b.x, b.y, b.z, b.w};
  union { unsigned short u16[8]; uint4 u4; } r;
#pragma unroll
  for (int j = 0; j < 8; j++) {
    unsigned u = __float_as_uint(v[j]);
    u += 0x7FFFu + ((u >> 16) & 1u);
    r.u16[j] = (unsigned short)(u >> 16);
  }
  *((uint4*)outp + i) = r.u4;
}

// -------- per-capsule Gram (W W^T + eps I) and Gauss-Jordan inverse ---------
// one block per capsule, 256 threads, thread t handles entry (d,e)=(t>>4,t&15)
__global__ __launch_bounds__(256) void gram_inv_kernel(
    const float* __restrict__ w, float* __restrict__ sigma) {
  int c = blockIdx.x;
  int t = threadIdx.x;
  int d = t >> 4, e = t & 15;
  __shared__ float ch[16][132];   // stride 132: float4-aligned, 2-way bank max
  __shared__ float G[16][17];
  __shared__ float IV[16][17];
  const float* wc = w + (size_t)c * D_DIM * F_DIM;
  float acc = 0.f;
  int lr = t >> 4;            // load row
  int lc = (t & 15) * 8;      // load col (8 floats per thread)
  for (int chunk = 0; chunk < F_DIM / 128; ++chunk) {
    __syncthreads();
    const float* src = wc + (size_t)lr * F_DIM + chunk * 128 + lc;
    float4 v0 = *(const float4*)src;
    float4 v1 = *(const float4*)(src + 4);
    *(float4*)&ch[lr][lc] = v0;
    *(float4*)&ch[lr][lc + 4] = v1;
    __syncthreads();
#pragma unroll 16
    for (int j = 0; j < 128; j++) acc = fmaf(ch[d][j], ch[e][j], acc);
  }
  G[d][e] = acc + (d == e ? RIDGE_EPS : 0.f);
  IV[d][e] = (d == e) ? 1.f : 0.f;
  __syncthreads();
  // Gauss-Jordan, no pivoting (SPD, diag ~1/3, ridge-regularized)
  for (int k = 0; k < 16; k++) {
    float piv = G[k][k];
    float gke = G[k][e];
    float ike = IV[k][e];
    float f   = G[d][k];
    float gde = G[d][e];
    float ide = IV[d][e];
    __syncthreads();
    if (d == k) {
      G[k][e]  = gke / piv;
      IV[k][e] = ike / piv;
    } else {
      G[d][e]  = gde - f * gke / piv;
      IV[d][e] = ide - f * ike / piv;
    }
    __syncthreads();
  }
  sigma[(size_t)c * 256 + t] = IV[d][e];
}

// ------------- fused bf16 MFMA GEMM (u = x W^T) + sqrt(u^T S u) -------------
// tile BM=128 x BN=64 (4 capsules), BK=64, 4 waves each 32x64 (2x4 frags)
// LDS rows are 128B with XOR ((r&7)<<4) swizzle; global_load_lds writes
// linearly, so the swizzle is applied on the per-lane GLOBAL source address
// (m173 pattern) and on the ds_read address — conflict-free ds_read_b128.
__global__ __launch_bounds__(256) void gemm_caps_kernel(
    const unsigned short* __restrict__ xb,   // [4096][2048] bf16
    const unsigned short* __restrict__ wb,   // [1600][2048] bf16
    const float* __restrict__ sigma,         // [100][16][16]
    float* __restrict__ out)                 // [4096][100]
{
  __shared__ __align__(16) unsigned char smem[37376];
  const int t = threadIdx.x;
  const int lane = t & 63;
  const int wid = t >> 6;
  const int bid = blockIdx.x;
  const int bn = bid % 25;          // 25 consecutive blocks share the A panel
  const int bm = bid / 25;
  const int rowBase = bm * 128;
  const int colBase = bn * 64;

  unsigned char* sA = smem;          // 128x64 bf16 = 16384 B
  unsigned char* sB = smem + 16384;  //  64x64 bf16 =  8192 B

  // staging: per wave 4 A-instrs + 2 B-instrs of 1KB (64 lanes x 16B)
  const unsigned short* srcA[4]; unsigned qA[4];
#pragma unroll
  for (int i = 0; i < 4; i++) {
    unsigned q = (unsigned)wid * 4096u + (unsigned)i * 1024u + (unsigned)lane * 16u;
    unsigned r = q >> 7, b = q & 127u;
    unsigned cb = b ^ ((r & 7u) << 4);          // inverse swizzle on source
    qA[i] = q;
    srcA[i] = xb + (size_t)(rowBase + (int)r) * F_DIM + (cb >> 1);
  }
  const unsigned short* srcB[2]; unsigned qB[2];
#pragma unroll
  for (int i = 0; i < 2; i++) {
    unsigned q = (unsigned)wid * 2048u + (unsigned)i * 1024u + (unsigned)lane * 16u;
    unsigned r = q >> 7, b = q & 127u;
    unsigned cb = b ^ ((r & 7u) << 4);
    qB[i] = q;
    srcB[i] = wb + (size_t)(colBase + (int)r) * F_DIM + (cb >> 1);
  }

  // swizzled ds_read addresses for MFMA fragments
  int aOff[2][2], bOff[4][2];
#pragma unroll
  for (int m = 0; m < 2; m++) {
    int r = wid * 32 + m * 16 + (lane & 15);
    int swz = (r & 7) << 4;
#pragma unroll
    for (int ks = 0; ks < 2; ks++) {
      int kb = ks * 64 + ((lane >> 4) << 4);
      aOff[m][ks] = r * 128 + (kb ^ swz);
    }
  }
#pragma unroll
  for (int n = 0; n < 4; n++) {
    int r = n * 16 + (lane & 15);
    int swz = (r & 7) << 4;
#pragma unroll
    for (int ks = 0; ks < 2; ks++) {
      int kb = ks * 64 + ((lane >> 4) << 4);
      bOff[n][ks] = r * 128 + (kb ^ swz);
    }
  }

  f32x4 acc[2][4];
#pragma unroll
  for (int m = 0; m < 2; m++)
#pragma unroll
    for (int n = 0; n < 4; n++)
      acc[m][n] = (f32x4){0.f, 0.f, 0.f, 0.f};

  for (int kt = 0; kt < F_DIM / 64; ++kt) {
    const size_t koff = (size_t)kt * 64;
#pragma unroll
    for (int i = 0; i < 4; i++) gload16(srcA[i] + koff, sA + qA[i]);
#pragma unroll
    for (int i = 0; i < 2; i++) gload16(srcB[i] + koff, sB + qB[i]);
    __syncthreads();   // drains vmcnt -> LDS tile ready
#pragma unroll
    for (int ks = 0; ks < 2; ks++) {
      bf16x8 a0 = *(const bf16x8*)(sA + aOff[0][ks]);
      bf16x8 a1 = *(const bf16x8*)(sA + aOff[1][ks]);
      bf16x8 b0 = *(const bf16x8*)(sB + bOff[0][ks]);
      bf16x8 b1 = *(const bf16x8*)(sB + bOff[1][ks]);
      bf16x8 b2 = *(const bf16x8*)(sB + bOff[2][ks]);
      bf16x8 b3 = *(const bf16x8*)(sB + bOff[3][ks]);
      acc[0][0] = __builtin_amdgcn_mfma_f32_16x16x32_bf16(a0, b0, acc[0][0], 0, 0, 0);
      acc[0][1] = __builtin_amdgcn_mfma_f32_16x16x32_bf16(a0, b1, acc[0][1], 0, 0, 0);
      acc[0][2] = __builtin_amdgcn_mfma_f32_16x16x32_bf16(a0, b2, acc[0][2], 0, 0, 0);
      acc[0][3] = __builtin_amdgcn_mfma_f32_16x16x32_bf16(a0, b3, acc[0][3], 0, 0, 0);
      acc[1][0] = __builtin_amdgcn_mfma_f32_16x16x32_bf16(a1, b0, acc[1][0], 0, 0, 0);
      acc[1][1] = __builtin_amdgcn_mfma_f32_16x16x32_bf16(a1, b1, acc[1][1], 0, 0, 0);
      acc[1][2] = __builtin_amdgcn_mfma_f32_16x16x32_bf16(a1, b2, acc[1][2], 0, 0, 0);
      acc[1][3] = __builtin_amdgcn_mfma_f32_16x16x32_bf16(a1, b3, acc[1][3], 0, 0, 0);
    }
    __syncthreads();   // all waves done reading before next stage
  }

  // ---- epilogue: u -> LDS, then out[b,c] = sqrt(u^T Sigma u) ----
  float* uT = (float*)smem;            // [128][65] fp32 (pad -> bank-spread)
  float* sg = (float*)(smem + 33280);  // [4][256] sigma for this block
#pragma unroll
  for (int m = 0; m < 2; m++)
#pragma unroll
    for (int n = 0; n < 4; n++)
#pragma unroll
      for (int j = 0; j < 4; j++) {
        int row = wid * 32 + m * 16 + ((lane >> 4) << 2) + j;  // C/D layout
        int col = n * 16 + (lane & 15);
        uT[row * 65 + col] = acc[m][n][j];
      }
  const int capBase = bn * 4;
  for (int i = t; i < 1024; i += 256)
    sg[i] = sigma[(size_t)capBase * 256 + i];
  __syncthreads();
#pragma unroll
  for (int pp = 0; pp < 2; ++pp) {
    int p = t + pp * 256;
    int row = p & 127, cl = p >> 7;
    const float* uu = uT + row * 65 + cl * 16;
    const float* s  = sg + cl * 256;
    float qf = 0.f;
#pragma unroll
    for (int dd = 0; dd < 16; ++dd) {
      float td = 0.f;
#pragma unroll
      for (int ee = 0; ee < 16; ++ee) td = fmaf(s[dd * 16 + ee], uu[ee], td);
      qf = fmaf(uu[dd], td, qf);
    }
    out[(size_t)(rowBase + row) * C_DIM + capBase + cl] = sqrtf(fmaxf(qf, 0.f));
  }
}

extern "C" void kernel_launch(void* const* d_in, const int* in_sizes, int n_in,
                              void* d_out, int out_size, void* d_ws, size_t ws_size,
                              hipStream_t stream) {
  const float* x = (const float*)d_in[0];   // [4096][2048]
  const float* w = (const float*)d_in[1];   // [100][16][2048]
  float* out = (float*)d_out;               // [4096][100]

  // workspace layout (all rewritten every call; no cross-call state)
  unsigned short* xb = (unsigned short*)d_ws;              // 16 MB
  unsigned short* wb = xb + (size_t)B_DIM * F_DIM;         // 6.25 MB
  float* sigma = (float*)(wb + (size_t)N_DIM * F_DIM);     // 100 KB

  int n8x = B_DIM * F_DIM / 8;
  int n8w = N_DIM * F_DIM / 8;
  cvt_bf16_kernel<<<(n8x + 255) / 256, 256, 0, stream>>>(x, xb, n8x);
  cvt_bf16_kernel<<<(n8w + 255) / 256, 256, 0, stream>>>(w, wb, n8w);
  gram_inv_kernel<<<C_DIM, 256, 0, stream>>>(w, sigma);
  gemm_caps_kernel<<<(B_DIM / 128) * (N_DIM / 64), 256, 0, stream>>>(xb, wb, sigma, out);
}

// Round 2
// 79.916 us; speedup vs baseline: 1.0928x; 1.0928x over previous
//
#include <hip/hip_runtime.h>
#include <hip/hip_bf16.h>
#include <math.h>

#define F_DIM 2048
#define B_DIM 4096
#define C_DIM 100
#define D_DIM 16
#define N_DIM (C_DIM*D_DIM)   // 1600
#define RIDGE_EPS 1e-4f

typedef __attribute__((ext_vector_type(8))) short bf16x8;
typedef __attribute__((ext_vector_type(4))) float f32x4;

__device__ __forceinline__ void gload16(const void* g, void* l) {
  __builtin_amdgcn_global_load_lds(
      (const __attribute__((address_space(1))) void*)g,
      (__attribute__((address_space(3))) void*)l,
      16, 0, 0);
}

// ---------- fp32 -> bf16 (RNE) convert for BOTH x and w, 8 elems/thread ----------
__global__ void cvt_bf16_kernel(const float* __restrict__ x, const float* __restrict__ w,
                                unsigned short* __restrict__ xb, unsigned short* __restrict__ wb,
                                int nx8, int nw8) {
  int i = blockIdx.x * blockDim.x + threadIdx.x;
  const float* in; unsigned short* outp; int idx;
  if (i < nx8) { in = x; outp = xb; idx = i; }
  else { idx = i - nx8; if (idx >= nw8) return; in = w; outp = wb; }
  const float4* p = (const float4*)in + (size_t)idx * 2;
  float4 a = p[0], b = p[1];
  float v[8] = {a.x, a.y, a.z, a.w, b.x, b.y, b.z, b.w};
  union { unsigned short u16[8]; uint4 u4; } r;
#pragma unroll
  for (int j = 0; j < 8; j++) {
    unsigned u = __float_as_uint(v[j]);
    u += 0x7FFFu + ((u >> 16) & 1u);
    r.u16[j] = (unsigned short)(u >> 16);
  }
  *((uint4*)outp + idx) = r.u4;
}

// -------- per-capsule Gram via MFMA (A-frag == B-frag) + 64-lane Gauss-Jordan --------
// one wave per capsule. frag: lane holds W[c][lane&15][k0 + (lane>>4)*8 .. +8]
__global__ __launch_bounds__(64) void gram_inv_kernel(
    const unsigned short* __restrict__ wb, float* __restrict__ sigma) {
  int c = blockIdx.x;
  int lane = threadIdx.x;
  const unsigned short* src = wb + (size_t)c * (D_DIM * F_DIM)
                                 + (size_t)(lane & 15) * F_DIM + ((lane >> 4) * 8);
  f32x4 g = {0.f, 0.f, 0.f, 0.f};
#pragma unroll 8
  for (int kt = 0; kt < F_DIM / 32; ++kt) {
    bf16x8 f = *(const bf16x8*)(src + kt * 32);
    g = __builtin_amdgcn_mfma_f32_16x16x32_bf16(f, f, g, 0, 0, 0);
  }
  // C/D layout: col = lane&15, row = (lane>>4)*4 + j  (G symmetric, transpose harmless)
  __shared__ float G[16][17];
  __shared__ float IV[16][17];
  int col = lane & 15;
#pragma unroll
  for (int j = 0; j < 4; j++) {
    int row = (lane >> 4) * 4 + j;
    G[row][col]  = g[j] + (row == col ? RIDGE_EPS : 0.f);
    IV[row][col] = (row == col) ? 1.f : 0.f;
  }
  __syncthreads();
  // lane owns entries (d = (lane>>4) + 4j, e = col); SPD + ridge -> no pivoting
  for (int k = 0; k < 16; k++) {
    float piv = G[k][k];
    float gke = G[k][col];
    float ike = IV[k][col];
    float fj[4], gj[4], ij[4];
#pragma unroll
    for (int j = 0; j < 4; j++) {
      int d = (lane >> 4) + 4 * j;
      fj[j] = G[d][k]; gj[j] = G[d][col]; ij[j] = IV[d][col];
    }
    __syncthreads();
    float rp = 1.f / piv;
#pragma unroll
    for (int j = 0; j < 4; j++) {
      int d = (lane >> 4) + 4 * j;
      if (d == k) { G[d][col] = gke * rp;            IV[d][col] = ike * rp; }
      else        { G[d][col] = gj[j] - fj[j] * gke * rp;
                    IV[d][col] = ij[j] - fj[j] * ike * rp; }
    }
    __syncthreads();
  }
#pragma unroll
  for (int j = 0; j < 4; j++) {
    int d = (lane >> 4) + 4 * j;
    sigma[(size_t)c * 256 + d * 16 + col] = IV[d][col];
  }
}

// ------------- fused bf16 MFMA GEMM (u = x W^T) + sqrt(u^T S u) -------------
// tile BM=256 x BN=64 (4 capsules), BK=64, 4 waves each 64x64 (4x4 frags, 32 MFMA/kt)
// LDS rows 128B, XOR ((r&7)<<4) swizzle applied on per-lane GLOBAL source (m173)
// and on ds_read addresses; global_load_lds dest stays linear.
__global__ __launch_bounds__(256) void gemm_caps_kernel(
    const unsigned short* __restrict__ xb,   // [4096][2048] bf16
    const unsigned short* __restrict__ wb,   // [1600][2048] bf16
    const float* __restrict__ sigma,         // [100][16][16]
    float* __restrict__ out)                 // [4096][100]
{
  __shared__ __align__(16) unsigned char smem[40960];
  const int t = threadIdx.x;
  const int lane = t & 63;
  const int wid = t >> 6;
  // bijective XCD swizzle: 400 blocks = 8 XCDs x 50
  const int bid = blockIdx.x;
  const int swz = (bid & 7) * 50 + (bid >> 3);
  const int bn = swz % 25;
  const int bm = swz / 25;
  const int rowBase = bm * 256;
  const int colBase = bn * 64;

  unsigned char* sA = smem;          // 256x64 bf16 = 32768 B
  unsigned char* sB = smem + 32768;  //  64x64 bf16 =  8192 B

  // staging: per wave 8 A-instrs + 2 B-instrs of 1KB (64 lanes x 16B)
  const unsigned short* srcA[8]; unsigned qA[8];
#pragma unroll
  for (int i = 0; i < 8; i++) {
    unsigned q = (unsigned)wid * 8192u + (unsigned)i * 1024u + (unsigned)lane * 16u;
    unsigned r = q >> 7, b = q & 127u;
    unsigned cb = b ^ ((r & 7u) << 4);          // inverse swizzle on source
    qA[i] = q;
    srcA[i] = xb + (size_t)(rowBase + (int)r) * F_DIM + (cb >> 1);
  }
  const unsigned short* srcB[2]; unsigned qB[2];
#pragma unroll
  for (int i = 0; i < 2; i++) {
    unsigned q = (unsigned)wid * 2048u + (unsigned)i * 1024u + (unsigned)lane * 16u;
    unsigned r = q >> 7, b = q & 127u;
    unsigned cb = b ^ ((r & 7u) << 4);
    qB[i] = q;
    srcB[i] = wb + (size_t)(colBase + (int)r) * F_DIM + (cb >> 1);
  }

  // swizzled ds_read addresses for MFMA fragments
  int aOff[4][2], bOff[4][2];
#pragma unroll
  for (int m = 0; m < 4; m++) {
    int r = wid * 64 + m * 16 + (lane & 15);
    int sw = (r & 7) << 4;
#pragma unroll
    for (int ks = 0; ks < 2; ks++) {
      int kb = ks * 64 + ((lane >> 4) << 4);
      aOff[m][ks] = r * 128 + (kb ^ sw);
    }
  }
#pragma unroll
  for (int n = 0; n < 4; n++) {
    int r = n * 16 + (lane & 15);
    int sw = (r & 7) << 4;
#pragma unroll
    for (int ks = 0; ks < 2; ks++) {
      int kb = ks * 64 + ((lane >> 4) << 4);
      bOff[n][ks] = r * 128 + (kb ^ sw);
    }
  }

  f32x4 acc[4][4];
#pragma unroll
  for (int m = 0; m < 4; m++)
#pragma unroll
    for (int n = 0; n < 4; n++)
      acc[m][n] = (f32x4){0.f, 0.f, 0.f, 0.f};

  for (int kt = 0; kt < F_DIM / 64; ++kt) {
    const size_t koff = (size_t)kt * 64;
#pragma unroll
    for (int i = 0; i < 8; i++) gload16(srcA[i] + koff, sA + qA[i]);
#pragma unroll
    for (int i = 0; i < 2; i++) gload16(srcB[i] + koff, sB + qB[i]);
    __syncthreads();   // drains vmcnt -> LDS tile ready
#pragma unroll
    for (int ks = 0; ks < 2; ks++) {
      bf16x8 a0 = *(const bf16x8*)(sA + aOff[0][ks]);
      bf16x8 a1 = *(const bf16x8*)(sA + aOff[1][ks]);
      bf16x8 a2 = *(const bf16x8*)(sA + aOff[2][ks]);
      bf16x8 a3 = *(const bf16x8*)(sA + aOff[3][ks]);
      bf16x8 b0 = *(const bf16x8*)(sB + bOff[0][ks]);
      bf16x8 b1 = *(const bf16x8*)(sB + bOff[1][ks]);
      bf16x8 b2 = *(const bf16x8*)(sB + bOff[2][ks]);
      bf16x8 b3 = *(const bf16x8*)(sB + bOff[3][ks]);
      acc[0][0] = __builtin_amdgcn_mfma_f32_16x16x32_bf16(a0, b0, acc[0][0], 0, 0, 0);
      acc[0][1] = __builtin_amdgcn_mfma_f32_16x16x32_bf16(a0, b1, acc[0][1], 0, 0, 0);
      acc[0][2] = __builtin_amdgcn_mfma_f32_16x16x32_bf16(a0, b2, acc[0][2], 0, 0, 0);
      acc[0][3] = __builtin_amdgcn_mfma_f32_16x16x32_bf16(a0, b3, acc[0][3], 0, 0, 0);
      acc[1][0] = __builtin_amdgcn_mfma_f32_16x16x32_bf16(a1, b0, acc[1][0], 0, 0, 0);
      acc[1][1] = __builtin_amdgcn_mfma_f32_16x16x32_bf16(a1, b1, acc[1][1], 0, 0, 0);
      acc[1][2] = __builtin_amdgcn_mfma_f32_16x16x32_bf16(a1, b2, acc[1][2], 0, 0, 0);
      acc[1][3] = __builtin_amdgcn_mfma_f32_16x16x32_bf16(a1, b3, acc[1][3], 0, 0, 0);
      acc[2][0] = __builtin_amdgcn_mfma_f32_16x16x32_bf16(a2, b0, acc[2][0], 0, 0, 0);
      acc[2][1] = __builtin_amdgcn_mfma_f32_16x16x32_bf16(a2, b1, acc[2][1], 0, 0, 0);
      acc[2][2] = __builtin_amdgcn_mfma_f32_16x16x32_bf16(a2, b2, acc[2][2], 0, 0, 0);
      acc[2][3] = __builtin_amdgcn_mfma_f32_16x16x32_bf16(a2, b3, acc[2][3], 0, 0, 0);
      acc[3][0] = __builtin_amdgcn_mfma_f32_16x16x32_bf16(a3, b0, acc[3][0], 0, 0, 0);
      acc[3][1] = __builtin_amdgcn_mfma_f32_16x16x32_bf16(a3, b1, acc[3][1], 0, 0, 0);
      acc[3][2] = __builtin_amdgcn_mfma_f32_16x16x32_bf16(a3, b2, acc[3][2], 0, 0, 0);
      acc[3][3] = __builtin_amdgcn_mfma_f32_16x16x32_bf16(a3, b3, acc[3][3], 0, 0, 0);
    }
    __syncthreads();   // all waves done reading before next stage
  }

  // ---- epilogue: two 128-row phases; u -> LDS, out[b,c] = sqrt(u^T Sigma u) ----
  float* uT = (float*)smem;            // [128][65] fp32
  float* sg = (float*)(smem + 33280);  // [4][256] sigma for this block
  const int capBase = bn * 4;
  for (int i = t; i < 1024; i += 256)
    sg[i] = sigma[(size_t)capBase * 256 + i];
  for (int p = 0; p < 2; p++) {
    if ((wid >> 1) == p) {
      int rloc = (wid & 1) * 64;
#pragma unroll
      for (int m = 0; m < 4; m++)
#pragma unroll
        for (int n = 0; n < 4; n++)
#pragma unroll
          for (int j = 0; j < 4; j++) {
            int row = rloc + m * 16 + ((lane >> 4) << 2) + j;  // C/D layout
            int colc = n * 16 + (lane & 15);
            uT[row * 65 + colc] = acc[m][n][j];
          }
    }
    __syncthreads();
#pragma unroll
    for (int pp = 0; pp < 2; ++pp) {
      int pi = t + pp * 256;
      int row = pi & 127, cl = pi >> 7;
      const float* uu = uT + row * 65 + cl * 16;
      const float* s  = sg + cl * 256;
      float qf = 0.f;
#pragma unroll
      for (int dd = 0; dd < 16; ++dd) {
        float td = 0.f;
#pragma unroll
        for (int ee = 0; ee < 16; ++ee) td = fmaf(s[dd * 16 + ee], uu[ee], td);
        qf = fmaf(uu[dd], td, qf);
      }
      out[(size_t)(rowBase + p * 128 + row) * C_DIM + capBase + cl] = sqrtf(fmaxf(qf, 0.f));
    }
    if (p == 0) __syncthreads();   // phase-0 reads done before phase-1 writes
  }
}

extern "C" void kernel_launch(void* const* d_in, const int* in_sizes, int n_in,
                              void* d_out, int out_size, void* d_ws, size_t ws_size,
                              hipStream_t stream) {
  const float* x = (const float*)d_in[0];   // [4096][2048]
  const float* w = (const float*)d_in[1];   // [100][16][2048]
  float* out = (float*)d_out;               // [4096][100]

  unsigned short* xb = (unsigned short*)d_ws;              // 16 MB
  unsigned short* wb = xb + (size_t)B_DIM * F_DIM;         // 6.25 MB
  float* sigma = (float*)(wb + (size_t)N_DIM * F_DIM);     // 100 KB

  int nx8 = B_DIM * F_DIM / 8;   // 1048576
  int nw8 = N_DIM * F_DIM / 8;   // 409600
  int nthreads = nx8 + nw8;
  cvt_bf16_kernel<<<(nthreads + 255) / 256, 256, 0, stream>>>(x, w, xb, wb, nx8, nw8);
  gram_inv_kernel<<<C_DIM, 64, 0, stream>>>(wb, sigma);
  gemm_caps_kernel<<<(B_DIM / 256) * (N_DIM / 64), 256, 0, stream>>>(xb, wb, sigma, out);
}

// Round 3
// 74.773 us; speedup vs baseline: 1.1679x; 1.0688x over previous
//
#include <hip/hip_runtime.h>
#include <hip/hip_bf16.h>
#include <math.h>

#define F_DIM 2048
#define B_DIM 4096
#define C_DIM 100
#define D_DIM 16
#define N_DIM (C_DIM*D_DIM)   // 1600
#define RIDGE_EPS 1e-4f

typedef __attribute__((ext_vector_type(8))) short bf16x8;
typedef __attribute__((ext_vector_type(4))) float f32x4;

__device__ __forceinline__ void gload16(const void* g, void* l) {
  __builtin_amdgcn_global_load_lds(
      (const __attribute__((address_space(1))) void*)g,
      (__attribute__((address_space(3))) void*)l,
      16, 0, 0);
}

// ---------- fp32 -> bf16 (RNE) convert for BOTH x and w, 8 elems/thread ----------
__global__ void cvt_bf16_kernel(const float* __restrict__ x, const float* __restrict__ w,
                                unsigned short* __restrict__ xb, unsigned short* __restrict__ wb,
                                int nx8, int nw8) {
  int i = blockIdx.x * blockDim.x + threadIdx.x;
  const float* in; unsigned short* outp; int idx;
  if (i < nx8) { in = x; outp = xb; idx = i; }
  else { idx = i - nx8; if (idx >= nw8) return; in = w; outp = wb; }
  const float4* p = (const float4*)in + (size_t)idx * 2;
  float4 a = p[0], b = p[1];
  float v[8] = {a.x, a.y, a.z, a.w, b.x, b.y, b.z, b.w};
  union { unsigned short u16[8]; uint4 u4; } r;
#pragma unroll
  for (int j = 0; j < 8; j++) {
    unsigned u = __float_as_uint(v[j]);
    u += 0x7FFFu + ((u >> 16) & 1u);
    r.u16[j] = (unsigned short)(u >> 16);
  }
  *((uint4*)outp + idx) = r.u4;
}

// -------- per-capsule Gram via MFMA (K split over 4 waves) + Gauss-Jordan --------
__global__ __launch_bounds__(256) void gram_inv_kernel(
    const unsigned short* __restrict__ wb, float* __restrict__ sigma) {
  int c = blockIdx.x;
  int t = threadIdx.x, lane = t & 63, wid = t >> 6;
  // frag: lane holds W[c][lane&15][k0 + (lane>>4)*8 .. +8]; wave handles K-chunk wid*512
  const unsigned short* src = wb + (size_t)c * (D_DIM * F_DIM)
                                 + (size_t)(lane & 15) * F_DIM + ((lane >> 4) * 8) + wid * 512;
  f32x4 g = {0.f, 0.f, 0.f, 0.f};
#pragma unroll
  for (int kt = 0; kt < 16; ++kt) {
    bf16x8 f = *(const bf16x8*)(src + kt * 32);
    g = __builtin_amdgcn_mfma_f32_16x16x32_bf16(f, f, g, 0, 0, 0);
  }
  __shared__ float part[4][64][4];
#pragma unroll
  for (int j = 0; j < 4; j++) part[wid][lane][j] = g[j];
  __shared__ float G[16][17];
  __shared__ float IV[16][17];
  int d = t >> 4, e = t & 15;
  IV[d][e] = (d == e) ? 1.f : 0.f;
  __syncthreads();
  if (t < 64) {
    int col = t & 15;
#pragma unroll
    for (int j = 0; j < 4; j++) {
      int row = (t >> 4) * 4 + j;   // C/D layout; G symmetric so transpose harmless
      float s4 = part[0][t][j] + part[1][t][j] + part[2][t][j] + part[3][t][j];
      G[row][col] = s4 + (row == col ? RIDGE_EPS : 0.f);
    }
  }
  __syncthreads();
  // Gauss-Jordan, no pivoting (SPD, diag ~1/3, ridge-regularized); t owns (d,e)
  for (int k = 0; k < 16; k++) {
    float piv = G[k][k];
    float gke = G[k][e];
    float ike = IV[k][e];
    float f   = G[d][k];
    float gde = G[d][e];
    float ide = IV[d][e];
    __syncthreads();
    if (d == k) {
      G[k][e]  = gke / piv;
      IV[k][e] = ike / piv;
    } else {
      G[d][e]  = gde - f * gke / piv;
      IV[d][e] = ide - f * ike / piv;
    }
    __syncthreads();
  }
  sigma[(size_t)c * 256 + t] = IV[d][e];
}

// ------------- fused bf16 MFMA GEMM (u = x W^T) + sqrt(u^T S u) -------------
// tile BM=128 x BN=64 (4 capsules), BK=64, 4 waves each 32x64 (2x4 frags)
// double-buffered LDS (2x24KB), 2-phase: stage(next) issued BEFORE ds_read+MFMA(cur),
// single barrier per K-step. XOR ((r&7)<<4) swizzle via pre-swizzled global src.
__global__ __launch_bounds__(256) void gemm_caps_kernel(
    const unsigned short* __restrict__ xb,   // [4096][2048] bf16
    const unsigned short* __restrict__ wb,   // [1600][2048] bf16
    const float* __restrict__ sigma,         // [100][16][16]
    float* __restrict__ out)                 // [4096][100]
{
  __shared__ __align__(16) unsigned char smem[49152];
  const int t = threadIdx.x;
  const int lane = t & 63;
  const int wid = t >> 6;
  // bijective XCD swizzle: 800 blocks = 8 XCDs x 100
  const int bid = blockIdx.x;
  const int swz = (bid & 7) * 100 + (bid >> 3);
  const int bn = swz % 25;          // 25 consecutive share the A panel
  const int bm = swz / 25;
  const int rowBase = bm * 128;
  const int colBase = bn * 64;

  // per-buffer layout: sA = buf+0 (128x64 bf16 = 16KB), sB = buf+16384 (64x64 = 8KB)
  unsigned char* buf0 = smem;
  unsigned char* buf1 = smem + 24576;

  // staging: per wave 4 A-instrs + 2 B-instrs of 1KB (64 lanes x 16B)
  const unsigned short* srcA[4]; unsigned qA[4];
#pragma unroll
  for (int i = 0; i < 4; i++) {
    unsigned q = (unsigned)wid * 4096u + (unsigned)i * 1024u + (unsigned)lane * 16u;
    unsigned r = q >> 7, b = q & 127u;
    unsigned cb = b ^ ((r & 7u) << 4);          // inverse swizzle on source
    qA[i] = q;
    srcA[i] = xb + (size_t)(rowBase + (int)r) * F_DIM + (cb >> 1);
  }
  const unsigned short* srcB[2]; unsigned qB[2];
#pragma unroll
  for (int i = 0; i < 2; i++) {
    unsigned q = (unsigned)wid * 2048u + (unsigned)i * 1024u + (unsigned)lane * 16u;
    unsigned r = q >> 7, b = q & 127u;
    unsigned cb = b ^ ((r & 7u) << 4);
    qB[i] = 16384u + q;
    srcB[i] = wb + (size_t)(colBase + (int)r) * F_DIM + (cb >> 1);
  }

  // swizzled ds_read byte offsets (relative to buffer base)
  int aOff[2][2], bOff[4][2];
#pragma unroll
  for (int m = 0; m < 2; m++) {
    int r = wid * 32 + m * 16 + (lane & 15);
    int sw = (r & 7) << 4;
#pragma unroll
    for (int ks = 0; ks < 2; ks++) {
      int kb = ks * 64 + ((lane >> 4) << 4);
      aOff[m][ks] = r * 128 + (kb ^ sw);
    }
  }
#pragma unroll
  for (int n = 0; n < 4; n++) {
    int r = n * 16 + (lane & 15);
    int sw = (r & 7) << 4;
#pragma unroll
    for (int ks = 0; ks < 2; ks++) {
      int kb = ks * 64 + ((lane >> 4) << 4);
      bOff[n][ks] = 16384 + r * 128 + (kb ^ sw);
    }
  }

  f32x4 acc[2][4];
#pragma unroll
  for (int m = 0; m < 2; m++)
#pragma unroll
    for (int n = 0; n < 4; n++)
      acc[m][n] = (f32x4){0.f, 0.f, 0.f, 0.f};

  auto stage = [&](unsigned char* buf, int kt) {
    const size_t koff = (size_t)kt * 64;
#pragma unroll
    for (int i = 0; i < 4; i++) gload16(srcA[i] + koff, buf + qA[i]);
#pragma unroll
    for (int i = 0; i < 2; i++) gload16(srcB[i] + koff, buf + qB[i]);
  };
  auto compute = [&](const unsigned char* buf) {
#pragma unroll
    for (int ks = 0; ks < 2; ks++) {
      bf16x8 a0 = *(const bf16x8*)(buf + aOff[0][ks]);
      bf16x8 a1 = *(const bf16x8*)(buf + aOff[1][ks]);
      bf16x8 b0 = *(const bf16x8*)(buf + bOff[0][ks]);
      bf16x8 b1 = *(const bf16x8*)(buf + bOff[1][ks]);
      bf16x8 b2 = *(const bf16x8*)(buf + bOff[2][ks]);
      bf16x8 b3 = *(const bf16x8*)(buf + bOff[3][ks]);
      acc[0][0] = __builtin_amdgcn_mfma_f32_16x16x32_bf16(a0, b0, acc[0][0], 0, 0, 0);
      acc[0][1] = __builtin_amdgcn_mfma_f32_16x16x32_bf16(a0, b1, acc[0][1], 0, 0, 0);
      acc[0][2] = __builtin_amdgcn_mfma_f32_16x16x32_bf16(a0, b2, acc[0][2], 0, 0, 0);
      acc[0][3] = __builtin_amdgcn_mfma_f32_16x16x32_bf16(a0, b3, acc[0][3], 0, 0, 0);
      acc[1][0] = __builtin_amdgcn_mfma_f32_16x16x32_bf16(a1, b0, acc[1][0], 0, 0, 0);
      acc[1][1] = __builtin_amdgcn_mfma_f32_16x16x32_bf16(a1, b1, acc[1][1], 0, 0, 0);
      acc[1][2] = __builtin_amdgcn_mfma_f32_16x16x32_bf16(a1, b2, acc[1][2], 0, 0, 0);
      acc[1][3] = __builtin_amdgcn_mfma_f32_16x16x32_bf16(a1, b3, acc[1][3], 0, 0, 0);
    }
  };

  // 2-phase pipeline over 32 K-steps, compile-time buffer identities
  stage(buf0, 0);
  __syncthreads();
  for (int kt = 0; kt < 30; kt += 2) {
    stage(buf1, kt + 1);
    compute(buf0);
    __syncthreads();
    stage(buf0, kt + 2);
    compute(buf1);
    __syncthreads();
  }
  stage(buf1, 31);
  compute(buf0);
  __syncthreads();
  compute(buf1);
  __syncthreads();   // all reads done before smem reuse

  // ---- epilogue: u -> LDS [128][68]; sigma via wave-uniform s_loads ----
  float* uT = (float*)smem;   // 128*68*4 = 34816 B
#pragma unroll
  for (int m = 0; m < 2; m++)
#pragma unroll
    for (int n = 0; n < 4; n++)
#pragma unroll
      for (int j = 0; j < 4; j++) {
        int row = wid * 32 + m * 16 + ((lane >> 4) << 2) + j;  // C/D layout
        int col = n * 16 + (lane & 15);
        uT[row * 68 + col] = acc[m][n][j];
      }
  __syncthreads();
  const int capBase = bn * 4;
#pragma unroll
  for (int pp = 0; pp < 2; ++pp) {
    int pi = t + pp * 256;
    int row = pi & 127;
    int cl = __builtin_amdgcn_readfirstlane(pi >> 7);  // wave-uniform capsule
    const float* uu = uT + row * 68 + cl * 16;
    f32x4 u0 = *(const f32x4*)(uu + 0);
    f32x4 u1 = *(const f32x4*)(uu + 4);
    f32x4 u2 = *(const f32x4*)(uu + 8);
    f32x4 u3 = *(const f32x4*)(uu + 12);
    float ur[16];
#pragma unroll
    for (int j = 0; j < 4; j++) { ur[j] = u0[j]; ur[4+j] = u1[j]; ur[8+j] = u2[j]; ur[12+j] = u3[j]; }
    const float* s = sigma + (size_t)(capBase + cl) * 256;   // scalar loads
    float qf = 0.f;
#pragma unroll
    for (int dd = 0; dd < 16; ++dd) {
      float td = 0.f;
#pragma unroll
      for (int ee = 0; ee < 16; ++ee) td = fmaf(s[dd * 16 + ee], ur[ee], td);
      qf = fmaf(ur[dd], td, qf);
    }
    out[(size_t)(rowBase + row) * C_DIM + capBase + cl] = sqrtf(fmaxf(qf, 0.f));
  }
}

extern "C" void kernel_launch(void* const* d_in, const int* in_sizes, int n_in,
                              void* d_out, int out_size, void* d_ws, size_t ws_size,
                              hipStream_t stream) {
  const float* x = (const float*)d_in[0];   // [4096][2048]
  const float* w = (const float*)d_in[1];   // [100][16][2048]
  float* out = (float*)d_out;               // [4096][100]

  unsigned short* xb = (unsigned short*)d_ws;              // 16 MB
  unsigned short* wb = xb + (size_t)B_DIM * F_DIM;         // 6.25 MB
  float* sigma = (float*)(wb + (size_t)N_DIM * F_DIM);     // 100 KB

  int nx8 = B_DIM * F_DIM / 8;   // 1048576
  int nw8 = N_DIM * F_DIM / 8;   // 409600
  int nthreads = nx8 + nw8;
  cvt_bf16_kernel<<<(nthreads + 255) / 256, 256, 0, stream>>>(x, w, xb, wb, nx8, nw8);
  gram_inv_kernel<<<C_DIM, 256, 0, stream>>>(wb, sigma);
  gemm_caps_kernel<<<(B_DIM / 128) * (N_DIM / 64), 256, 0, stream>>>(xb, wb, sigma, out);
}

// Round 4
// 68.440 us; speedup vs baseline: 1.2760x; 1.0925x over previous
//
#include <hip/hip_runtime.h>
#include <hip/hip_bf16.h>
#include <math.h>

#define F_DIM 2048
#define B_DIM 4096
#define C_DIM 100
#define D_DIM 16
#define N_DIM (C_DIM*D_DIM)   // 1600
#define RIDGE_EPS 1e-4f

typedef __attribute__((ext_vector_type(8))) short bf16x8;
typedef __attribute__((ext_vector_type(4))) float f32x4;

__device__ __forceinline__ void gload16(const void* g, void* l) {
  __builtin_amdgcn_global_load_lds(
      (const __attribute__((address_space(1))) void*)g,
      (__attribute__((address_space(3))) void*)l,
      16, 0, 0);
}

// counted-vmcnt barrier: wait until <=N vmem ops outstanding, then s_barrier.
// "memory" clobber keeps ds_read/global_load_lds from crossing.
#define VM_BAR(N) asm volatile("s_waitcnt vmcnt(" #N ")\n\ts_barrier" ::: "memory")
#define LGKM_BAR() asm volatile("s_waitcnt lgkmcnt(0)\n\ts_barrier" ::: "memory")

// ---------- fp32 -> bf16 (RNE) convert for BOTH x and w, 8 elems/thread ----------
__global__ void cvt_bf16_kernel(const float* __restrict__ x, const float* __restrict__ w,
                                unsigned short* __restrict__ xb, unsigned short* __restrict__ wb,
                                int nx8, int nw8) {
  int i = blockIdx.x * blockDim.x + threadIdx.x;
  const float* in; unsigned short* outp; int idx;
  if (i < nx8) { in = x; outp = xb; idx = i; }
  else { idx = i - nx8; if (idx >= nw8) return; in = w; outp = wb; }
  const float4* p = (const float4*)in + (size_t)idx * 2;
  float4 a = p[0], b = p[1];
  float v[8] = {a.x, a.y, a.z, a.w, b.x, b.y, b.z, b.w};
  union { unsigned short u16[8]; uint4 u4; } r;
#pragma unroll
  for (int j = 0; j < 8; j++) {
    unsigned u = __float_as_uint(v[j]);
    u += 0x7FFFu + ((u >> 16) & 1u);
    r.u16[j] = (unsigned short)(u >> 16);
  }
  *((uint4*)outp + idx) = r.u4;
}

// -------- per-capsule Gram via MFMA (K split over 4 waves) + Gauss-Jordan --------
__global__ __launch_bounds__(256) void gram_inv_kernel(
    const unsigned short* __restrict__ wb, float* __restrict__ sigma) {
  int c = blockIdx.x;
  int t = threadIdx.x, lane = t & 63, wid = t >> 6;
  const unsigned short* src = wb + (size_t)c * (D_DIM * F_DIM)
                                 + (size_t)(lane & 15) * F_DIM + ((lane >> 4) * 8) + wid * 512;
  f32x4 g = {0.f, 0.f, 0.f, 0.f};
#pragma unroll
  for (int kt = 0; kt < 16; ++kt) {
    bf16x8 f = *(const bf16x8*)(src + kt * 32);
    g = __builtin_amdgcn_mfma_f32_16x16x32_bf16(f, f, g, 0, 0, 0);
  }
  __shared__ float part[4][64][4];
#pragma unroll
  for (int j = 0; j < 4; j++) part[wid][lane][j] = g[j];
  __shared__ float G[16][17];
  __shared__ float IV[16][17];
  int d = t >> 4, e = t & 15;
  IV[d][e] = (d == e) ? 1.f : 0.f;
  __syncthreads();
  if (t < 64) {
    int col = t & 15;
#pragma unroll
    for (int j = 0; j < 4; j++) {
      int row = (t >> 4) * 4 + j;   // C/D layout; G symmetric so transpose harmless
      float s4 = part[0][t][j] + part[1][t][j] + part[2][t][j] + part[3][t][j];
      G[row][col] = s4 + (row == col ? RIDGE_EPS : 0.f);
    }
  }
  __syncthreads();
  for (int k = 0; k < 16; k++) {
    float piv = G[k][k];
    float gke = G[k][e];
    float ike = IV[k][e];
    float f   = G[d][k];
    float gde = G[d][e];
    float ide = IV[d][e];
    __syncthreads();
    if (d == k) {
      G[k][e]  = gke / piv;
      IV[k][e] = ike / piv;
    } else {
      G[d][e]  = gde - f * gke / piv;
      IV[d][e] = ide - f * ike / piv;
    }
    __syncthreads();
  }
  sigma[(size_t)c * 256 + t] = IV[d][e];
}

// ------------- fused bf16 MFMA GEMM (u = x W^T) + sqrt(u^T S u) -------------
// tile BM=128 x BN=64 (4 capsules), BK=64, 4 waves each 32x64 (2x4 frags)
// double-buffered LDS, counted-vmcnt raw-barrier pipeline (AITER/T4 pattern):
// per K-step: {stage(next,6 loads); vmcnt(6)+bar; ds_read+MFMA(cur); lgkm0+bar}
// -> 6 prefetch loads stay in flight ACROSS the barrier, never drained to 0.
__global__ __launch_bounds__(256) void gemm_caps_kernel(
    const unsigned short* __restrict__ xb,   // [4096][2048] bf16
    const unsigned short* __restrict__ wb,   // [1600][2048] bf16
    const float* __restrict__ sigma,         // [100][16][16]
    float* __restrict__ out)                 // [4096][100]
{
  __shared__ __align__(16) unsigned char smem[49152];
  const int t = threadIdx.x;
  const int lane = t & 63;
  const int wid = t >> 6;
  // bijective XCD swizzle: 800 blocks = 8 XCDs x 100
  const int bid = blockIdx.x;
  const int swz = (bid & 7) * 100 + (bid >> 3);
  const int bn = swz % 25;          // 25 consecutive share the A panel
  const int bm = swz / 25;
  const int rowBase = bm * 128;
  const int colBase = bn * 64;

  unsigned char* buf0 = smem;
  unsigned char* buf1 = smem + 24576;

  const unsigned short* srcA[4]; unsigned qA[4];
#pragma unroll
  for (int i = 0; i < 4; i++) {
    unsigned q = (unsigned)wid * 4096u + (unsigned)i * 1024u + (unsigned)lane * 16u;
    unsigned r = q >> 7, b = q & 127u;
    unsigned cb = b ^ ((r & 7u) << 4);          // inverse swizzle on source
    qA[i] = q;
    srcA[i] = xb + (size_t)(rowBase + (int)r) * F_DIM + (cb >> 1);
  }
  const unsigned short* srcB[2]; unsigned qB[2];
#pragma unroll
  for (int i = 0; i < 2; i++) {
    unsigned q = (unsigned)wid * 2048u + (unsigned)i * 1024u + (unsigned)lane * 16u;
    unsigned r = q >> 7, b = q & 127u;
    unsigned cb = b ^ ((r & 7u) << 4);
    qB[i] = 16384u + q;
    srcB[i] = wb + (size_t)(colBase + (int)r) * F_DIM + (cb >> 1);
  }

  int aOff[2][2], bOff[4][2];
#pragma unroll
  for (int m = 0; m < 2; m++) {
    int r = wid * 32 + m * 16 + (lane & 15);
    int sw = (r & 7) << 4;
#pragma unroll
    for (int ks = 0; ks < 2; ks++) {
      int kb = ks * 64 + ((lane >> 4) << 4);
      aOff[m][ks] = r * 128 + (kb ^ sw);
    }
  }
#pragma unroll
  for (int n = 0; n < 4; n++) {
    int r = n * 16 + (lane & 15);
    int sw = (r & 7) << 4;
#pragma unroll
    for (int ks = 0; ks < 2; ks++) {
      int kb = ks * 64 + ((lane >> 4) << 4);
      bOff[n][ks] = 16384 + r * 128 + (kb ^ sw);
    }
  }

  f32x4 acc[2][4];
#pragma unroll
  for (int m = 0; m < 2; m++)
#pragma unroll
    for (int n = 0; n < 4; n++)
      acc[m][n] = (f32x4){0.f, 0.f, 0.f, 0.f};

  auto stage = [&](unsigned char* buf, int kt) {
    const size_t koff = (size_t)kt * 64;
#pragma unroll
    for (int i = 0; i < 4; i++) gload16(srcA[i] + koff, buf + qA[i]);
#pragma unroll
    for (int i = 0; i < 2; i++) gload16(srcB[i] + koff, buf + qB[i]);
  };
  auto compute = [&](const unsigned char* buf) {
#pragma unroll
    for (int ks = 0; ks < 2; ks++) {
      bf16x8 a0 = *(const bf16x8*)(buf + aOff[0][ks]);
      bf16x8 a1 = *(const bf16x8*)(buf + aOff[1][ks]);
      bf16x8 b0 = *(const bf16x8*)(buf + bOff[0][ks]);
      bf16x8 b1 = *(const bf16x8*)(buf + bOff[1][ks]);
      bf16x8 b2 = *(const bf16x8*)(buf + bOff[2][ks]);
      bf16x8 b3 = *(const bf16x8*)(buf + bOff[3][ks]);
      acc[0][0] = __builtin_amdgcn_mfma_f32_16x16x32_bf16(a0, b0, acc[0][0], 0, 0, 0);
      acc[0][1] = __builtin_amdgcn_mfma_f32_16x16x32_bf16(a0, b1, acc[0][1], 0, 0, 0);
      acc[0][2] = __builtin_amdgcn_mfma_f32_16x16x32_bf16(a0, b2, acc[0][2], 0, 0, 0);
      acc[0][3] = __builtin_amdgcn_mfma_f32_16x16x32_bf16(a0, b3, acc[0][3], 0, 0, 0);
      acc[1][0] = __builtin_amdgcn_mfma_f32_16x16x32_bf16(a1, b0, acc[1][0], 0, 0, 0);
      acc[1][1] = __builtin_amdgcn_mfma_f32_16x16x32_bf16(a1, b1, acc[1][1], 0, 0, 0);
      acc[1][2] = __builtin_amdgcn_mfma_f32_16x16x32_bf16(a1, b2, acc[1][2], 0, 0, 0);
      acc[1][3] = __builtin_amdgcn_mfma_f32_16x16x32_bf16(a1, b3, acc[1][3], 0, 0, 0);
    }
  };

  // counted-vmcnt pipeline over 32 K-steps (each wave: exactly 6 loads/K-step)
  stage(buf0, 0);                 // 6 outstanding
  for (int kt = 0; kt < 30; kt += 2) {
    stage(buf1, kt + 1);          // <=12 outstanding
    VM_BAR(6);                    // tile kt's 6 loads landed; kt+1's in flight
    compute(buf0);
    LGKM_BAR();                   // all reads of buf0 retired before re-stage
    stage(buf0, kt + 2);
    VM_BAR(6);
    compute(buf1);
    LGKM_BAR();
  }
  stage(buf1, 31);
  VM_BAR(6);
  compute(buf0);                  // kt=30
  LGKM_BAR();
  VM_BAR(0);                      // drain: tile 31 loads done
  compute(buf1);                  // kt=31
  LGKM_BAR();                     // all LDS reads done before smem reuse

  // ---- epilogue: u -> LDS [128][68]; sigma via wave-uniform s_loads ----
  float* uT = (float*)smem;   // 128*68*4 = 34816 B
#pragma unroll
  for (int m = 0; m < 2; m++)
#pragma unroll
    for (int n = 0; n < 4; n++)
#pragma unroll
      for (int j = 0; j < 4; j++) {
        int row = wid * 32 + m * 16 + ((lane >> 4) << 2) + j;  // C/D layout
        int col = n * 16 + (lane & 15);
        uT[row * 68 + col] = acc[m][n][j];
      }
  __syncthreads();
  const int capBase = bn * 4;
#pragma unroll
  for (int pp = 0; pp < 2; ++pp) {
    int pi = t + pp * 256;
    int row = pi & 127;
    int cl = __builtin_amdgcn_readfirstlane(pi >> 7);  // wave-uniform capsule
    const float* uu = uT + row * 68 + cl * 16;
    f32x4 u0 = *(const f32x4*)(uu + 0);
    f32x4 u1 = *(const f32x4*)(uu + 4);
    f32x4 u2 = *(const f32x4*)(uu + 8);
    f32x4 u3 = *(const f32x4*)(uu + 12);
    float ur[16];
#pragma unroll
    for (int j = 0; j < 4; j++) { ur[j] = u0[j]; ur[4+j] = u1[j]; ur[8+j] = u2[j]; ur[12+j] = u3[j]; }
    const float* s = sigma + (size_t)(capBase + cl) * 256;   // scalar loads
    float qf = 0.f;
#pragma unroll
    for (int dd = 0; dd < 16; ++dd) {
      float td = 0.f;
#pragma unroll
      for (int ee = 0; ee < 16; ++ee) td = fmaf(s[dd * 16 + ee], ur[ee], td);
      qf = fmaf(ur[dd], td, qf);
    }
    out[(size_t)(rowBase + row) * C_DIM + capBase + cl] = sqrtf(fmaxf(qf, 0.f));
  }
}

extern "C" void kernel_launch(void* const* d_in, const int* in_sizes, int n_in,
                              void* d_out, int out_size, void* d_ws, size_t ws_size,
                              hipStream_t stream) {
  const float* x = (const float*)d_in[0];   // [4096][2048]
  const float* w = (const float*)d_in[1];   // [100][16][2048]
  float* out = (float*)d_out;               // [4096][100]

  unsigned short* xb = (unsigned short*)d_ws;              // 16 MB
  unsigned short* wb = xb + (size_t)B_DIM * F_DIM;         // 6.25 MB
  float* sigma = (float*)(wb + (size_t)N_DIM * F_DIM);     // 100 KB

  int nx8 = B_DIM * F_DIM / 8;   // 1048576
  int nw8 = N_DIM * F_DIM / 8;   // 409600
  int nthreads = nx8 + nw8;
  cvt_bf16_kernel<<<(nthreads + 255) / 256, 256, 0, stream>>>(x, w, xb, wb, nx8, nw8);
  gram_inv_kernel<<<C_DIM, 256, 0, stream>>>(wb, sigma);
  gemm_caps_kernel<<<(B_DIM / 128) * (N_DIM / 64), 256, 0, stream>>>(xb, wb, sigma, out);
}

// Round 5
// 56.811 us; speedup vs baseline: 1.5372x; 1.2047x over previous
//
#include <hip/hip_runtime.h>
#include <hip/hip_bf16.h>
#include <math.h>

#define F_DIM 2048
#define B_DIM 4096
#define C_DIM 100
#define D_DIM 16
#define N_DIM (C_DIM*D_DIM)   // 1600
#define N_PAD 1664            // 13 tiles of 128
#define RIDGE_EPS 1e-4f

typedef __attribute__((ext_vector_type(8))) short bf16x8;
typedef __attribute__((ext_vector_type(4))) float f32x4;

__device__ __forceinline__ void gload16(const void* g, void* l) {
  __builtin_amdgcn_global_load_lds(
      (const __attribute__((address_space(1))) void*)g,
      (__attribute__((address_space(3))) void*)l,
      16, 0, 0);
}

// counted-vmcnt barrier: wait until <=N vmem ops outstanding, then s_barrier.
#define VM_BAR(N) asm volatile("s_waitcnt vmcnt(" #N ")\n\ts_barrier" ::: "memory")
#define LGKM_BAR() asm volatile("s_waitcnt lgkmcnt(0)\n\ts_barrier" ::: "memory")

__device__ __forceinline__ unsigned short f2bf(float f) {
  unsigned u = __float_as_uint(f);
  u += 0x7FFFu + ((u >> 16) & 1u);
  return (unsigned short)(u >> 16);
}

// ---- fused: blocks 0..99 = per-capsule Gram+inverse (reads fp32 w directly);
//      blocks 100.. = fp32->bf16 convert of x and w + zero-pad of wb rows ----
__global__ __launch_bounds__(256) void cvt_gram_kernel(
    const float* __restrict__ x, const float* __restrict__ w,
    unsigned short* __restrict__ xb, unsigned short* __restrict__ wb,
    float* __restrict__ sigma, int nx8, int nw8, int npad8) {
  __shared__ float part[4][64][4];
  __shared__ float G[16][17];
  __shared__ float IV[16][17];
  int t = threadIdx.x;
  if (blockIdx.x < C_DIM) {
    // ---------------- gram + Gauss-Jordan inverse ----------------
    int c = blockIdx.x;
    int lane = t & 63, wid = t >> 6;
    const float* src = w + (size_t)c * (D_DIM * F_DIM)
                         + (size_t)(lane & 15) * F_DIM + ((lane >> 4) * 8) + wid * 512;
    f32x4 g = {0.f, 0.f, 0.f, 0.f};
#pragma unroll
    for (int kt = 0; kt < 16; ++kt) {
      float4 v0 = *(const float4*)(src + kt * 32);
      float4 v1 = *(const float4*)(src + kt * 32 + 4);
      bf16x8 f;
      f[0] = (short)f2bf(v0.x); f[1] = (short)f2bf(v0.y);
      f[2] = (short)f2bf(v0.z); f[3] = (short)f2bf(v0.w);
      f[4] = (short)f2bf(v1.x); f[5] = (short)f2bf(v1.y);
      f[6] = (short)f2bf(v1.z); f[7] = (short)f2bf(v1.w);
      g = __builtin_amdgcn_mfma_f32_16x16x32_bf16(f, f, g, 0, 0, 0);
    }
#pragma unroll
    for (int j = 0; j < 4; j++) part[wid][lane][j] = g[j];
    int d = t >> 4, e = t & 15;
    IV[d][e] = (d == e) ? 1.f : 0.f;
    __syncthreads();
    if (t < 64) {
      int col = t & 15;
#pragma unroll
      for (int j = 0; j < 4; j++) {
        int row = (t >> 4) * 4 + j;   // C/D layout; G symmetric so transpose harmless
        float s4 = part[0][t][j] + part[1][t][j] + part[2][t][j] + part[3][t][j];
        G[row][col] = s4 + (row == col ? RIDGE_EPS : 0.f);
      }
    }
    __syncthreads();
    for (int k = 0; k < 16; k++) {
      float piv = G[k][k];
      float gke = G[k][e];
      float ike = IV[k][e];
      float f   = G[d][k];
      float gde = G[d][e];
      float ide = IV[d][e];
      __syncthreads();
      if (d == k) {
        G[k][e]  = gke / piv;
        IV[k][e] = ike / piv;
      } else {
        G[d][e]  = gde - f * gke / piv;
        IV[d][e] = ide - f * ike / piv;
      }
      __syncthreads();
    }
    sigma[(size_t)c * 256 + t] = IV[d][e];
    return;
  }
  // ---------------- converts ----------------
  int i = (blockIdx.x - C_DIM) * 256 + t;
  const float* in; unsigned short* outp; int idx;
  if (i < nx8) { in = x; outp = xb; idx = i; }
  else {
    idx = i - nx8;
    if (idx >= nw8) {
      int idx3 = idx - nw8;
      if (idx3 < npad8) {  // zero-fill wb pad rows 1600..1663
        uint4 z = {0, 0, 0, 0};
        *((uint4*)(wb + (size_t)N_DIM * F_DIM) + idx3) = z;
      }
      return;
    }
    in = w; outp = wb;
  }
  const float4* p = (const float4*)in + (size_t)idx * 2;
  float4 a = p[0], b = p[1];
  float v[8] = {a.x, a.y, a.z, a.w, b.x, b.y, b.z, b.w};
  union { unsigned short u16[8]; uint4 u4; } r;
#pragma unroll
  for (int j = 0; j < 8; j++) r.u16[j] = f2bf(v[j]);
  *((uint4*)outp + idx) = r.u4;
}

// ------------- fused bf16 MFMA GEMM (u = x W^T) + sqrt(u^T S u) -------------
// tile BM=128 x BN=128 (8 capsules), BK=64, 4 waves 2x2, each 64x64 (4x4 frags)
// LDS bytes/FLOP = 1/64+1/64 (33% less than 32x64 wave tiles). Double-buffered,
// counted-vmcnt pipeline: {stage(next,8); vmcnt(8)+bar; ds_read+MFMA; lgkm0+bar}.
__global__ __launch_bounds__(256) void gemm_caps_kernel(
    const unsigned short* __restrict__ xb,   // [4096][2048] bf16
    const unsigned short* __restrict__ wb,   // [1664][2048] bf16 (rows>=1600 zero)
    const float* __restrict__ sigma,         // [100][16][16]
    float* __restrict__ out)                 // [4096][100]
{
  __shared__ __align__(16) unsigned char smem[65536];
  const int t = threadIdx.x;
  const int lane = t & 63;
  const int wid = t >> 6;
  const int wr = wid >> 1, wc = wid & 1;    // 2x2 wave grid
  // bijective XCD swizzle: 416 blocks = 8 XCDs x 52
  const int bid = blockIdx.x;
  const int swz = (bid & 7) * 52 + (bid >> 3);
  const int bn = swz % 13;          // 13 consecutive share the A panel
  const int bm = swz / 13;
  const int rowBase = bm * 128;
  const int colBase = bn * 128;

  unsigned char* buf0 = smem;
  unsigned char* buf1 = smem + 32768;
  // per-buffer: sA = buf (128x64 = 16KB), sB = buf+16384 (128x64 = 16KB)

  // staging: per wave 4 A + 4 B gloads of 1KB (64 lanes x 16B)
  const unsigned short* srcA[4]; unsigned qA[4];
  const unsigned short* srcB[4]; unsigned qB[4];
#pragma unroll
  for (int i = 0; i < 4; i++) {
    unsigned q = (unsigned)wid * 4096u + (unsigned)i * 1024u + (unsigned)lane * 16u;
    unsigned r = q >> 7, b = q & 127u;
    unsigned cb = b ^ ((r & 7u) << 4);          // inverse swizzle on source
    qA[i] = q;
    srcA[i] = xb + (size_t)(rowBase + (int)r) * F_DIM + (cb >> 1);
    qB[i] = 16384u + q;
    srcB[i] = wb + (size_t)(colBase + (int)r) * F_DIM + (cb >> 1);
  }

  // swizzled ds_read byte offsets (relative to buffer base)
  int aOff[4][2], bOff[4][2];
#pragma unroll
  for (int m = 0; m < 4; m++) {
    int r = wr * 64 + m * 16 + (lane & 15);
    int sw = (r & 7) << 4;
#pragma unroll
    for (int ks = 0; ks < 2; ks++) {
      int kb = ks * 64 + ((lane >> 4) << 4);
      aOff[m][ks] = r * 128 + (kb ^ sw);
    }
  }
#pragma unroll
  for (int n = 0; n < 4; n++) {
    int r = wc * 64 + n * 16 + (lane & 15);
    int sw = (r & 7) << 4;
#pragma unroll
    for (int ks = 0; ks < 2; ks++) {
      int kb = ks * 64 + ((lane >> 4) << 4);
      bOff[n][ks] = 16384 + r * 128 + (kb ^ sw);
    }
  }

  f32x4 acc[4][4];
#pragma unroll
  for (int m = 0; m < 4; m++)
#pragma unroll
    for (int n = 0; n < 4; n++)
      acc[m][n] = (f32x4){0.f, 0.f, 0.f, 0.f};

  auto stage = [&](unsigned char* buf, int kt) {
    const size_t koff = (size_t)kt * 64;
#pragma unroll
    for (int i = 0; i < 4; i++) gload16(srcA[i] + koff, buf + qA[i]);
#pragma unroll
    for (int i = 0; i < 4; i++) gload16(srcB[i] + koff, buf + qB[i]);
  };
  auto compute = [&](const unsigned char* buf) {
#pragma unroll
    for (int ks = 0; ks < 2; ks++) {
      bf16x8 a0 = *(const bf16x8*)(buf + aOff[0][ks]);
      bf16x8 a1 = *(const bf16x8*)(buf + aOff[1][ks]);
      bf16x8 a2 = *(const bf16x8*)(buf + aOff[2][ks]);
      bf16x8 a3 = *(const bf16x8*)(buf + aOff[3][ks]);
      bf16x8 b0 = *(const bf16x8*)(buf + bOff[0][ks]);
      bf16x8 b1 = *(const bf16x8*)(buf + bOff[1][ks]);
      bf16x8 b2 = *(const bf16x8*)(buf + bOff[2][ks]);
      bf16x8 b3 = *(const bf16x8*)(buf + bOff[3][ks]);
      __builtin_amdgcn_s_setprio(1);
      acc[0][0] = __builtin_amdgcn_mfma_f32_16x16x32_bf16(a0, b0, acc[0][0], 0, 0, 0);
      acc[0][1] = __builtin_amdgcn_mfma_f32_16x16x32_bf16(a0, b1, acc[0][1], 0, 0, 0);
      acc[0][2] = __builtin_amdgcn_mfma_f32_16x16x32_bf16(a0, b2, acc[0][2], 0, 0, 0);
      acc[0][3] = __builtin_amdgcn_mfma_f32_16x16x32_bf16(a0, b3, acc[0][3], 0, 0, 0);
      acc[1][0] = __builtin_amdgcn_mfma_f32_16x16x32_bf16(a1, b0, acc[1][0], 0, 0, 0);
      acc[1][1] = __builtin_amdgcn_mfma_f32_16x16x32_bf16(a1, b1, acc[1][1], 0, 0, 0);
      acc[1][2] = __builtin_amdgcn_mfma_f32_16x16x32_bf16(a1, b2, acc[1][2], 0, 0, 0);
      acc[1][3] = __builtin_amdgcn_mfma_f32_16x16x32_bf16(a1, b3, acc[1][3], 0, 0, 0);
      acc[2][0] = __builtin_amdgcn_mfma_f32_16x16x32_bf16(a2, b0, acc[2][0], 0, 0, 0);
      acc[2][1] = __builtin_amdgcn_mfma_f32_16x16x32_bf16(a2, b1, acc[2][1], 0, 0, 0);
      acc[2][2] = __builtin_amdgcn_mfma_f32_16x16x32_bf16(a2, b2, acc[2][2], 0, 0, 0);
      acc[2][3] = __builtin_amdgcn_mfma_f32_16x16x32_bf16(a2, b3, acc[2][3], 0, 0, 0);
      acc[3][0] = __builtin_amdgcn_mfma_f32_16x16x32_bf16(a3, b0, acc[3][0], 0, 0, 0);
      acc[3][1] = __builtin_amdgcn_mfma_f32_16x16x32_bf16(a3, b1, acc[3][1], 0, 0, 0);
      acc[3][2] = __builtin_amdgcn_mfma_f32_16x16x32_bf16(a3, b2, acc[3][2], 0, 0, 0);
      acc[3][3] = __builtin_amdgcn_mfma_f32_16x16x32_bf16(a3, b3, acc[3][3], 0, 0, 0);
      __builtin_amdgcn_s_setprio(0);
    }
  };

  // counted-vmcnt pipeline over 32 K-steps (each wave: exactly 8 loads/K-step)
  stage(buf0, 0);
  for (int kt = 0; kt < 30; kt += 2) {
    stage(buf1, kt + 1);
    VM_BAR(8);
    compute(buf0);
    LGKM_BAR();
    stage(buf0, kt + 2);
    VM_BAR(8);
    compute(buf1);
    LGKM_BAR();
  }
  stage(buf1, 31);
  VM_BAR(8);
  compute(buf0);
  LGKM_BAR();
  VM_BAR(0);
  compute(buf1);
  LGKM_BAR();   // all LDS reads done before smem reuse

  // ---- epilogue: u -> LDS [128][128] with XOR-granule swizzle ----
  float* uT = (float*)smem;
#pragma unroll
  for (int m = 0; m < 4; m++)
#pragma unroll
    for (int n = 0; n < 4; n++)
#pragma unroll
      for (int j = 0; j < 4; j++) {
        int row = wr * 64 + m * 16 + ((lane >> 4) << 2) + j;  // C/D layout
        int col = wc * 64 + n * 16 + (lane & 15);
        int g = (col >> 2) ^ ((row & 7) << 2);
        uT[row * 128 + g * 4 + (col & 3)] = acc[m][n][j];
      }
  __syncthreads();
  const int capBase = bn * 8;
#pragma unroll
  for (int pp = 0; pp < 4; ++pp) {
    int pi = t + pp * 256;
    int row = pi & 127;
    int cl = __builtin_amdgcn_readfirstlane(pi >> 7);  // wave-uniform capsule
    float ur[16];
#pragma unroll
    for (int q = 0; q < 4; q++) {
      int g = (cl * 4 + q) ^ ((row & 7) << 2);
      f32x4 v = *(const f32x4*)(uT + row * 128 + g * 4);
#pragma unroll
      for (int j = 0; j < 4; j++) ur[q * 4 + j] = v[j];
    }
    int cap = capBase + cl;
    const float* s = sigma + (size_t)cap * 256;   // wave-uniform -> s_loads
    float qf = 0.f;
#pragma unroll
    for (int dd = 0; dd < 16; ++dd) {
      float td = 0.f;
#pragma unroll
      for (int ee = 0; ee < 16; ++ee) td = fmaf(s[dd * 16 + ee], ur[ee], td);
      qf = fmaf(ur[dd], td, qf);
    }
    if (cap < C_DIM)
      out[(size_t)(rowBase + row) * C_DIM + cap] = sqrtf(fmaxf(qf, 0.f));
  }
}

extern "C" void kernel_launch(void* const* d_in, const int* in_sizes, int n_in,
                              void* d_out, int out_size, void* d_ws, size_t ws_size,
                              hipStream_t stream) {
  const float* x = (const float*)d_in[0];   // [4096][2048]
  const float* w = (const float*)d_in[1];   // [100][16][2048]
  float* out = (float*)d_out;               // [4096][100]

  unsigned short* xb = (unsigned short*)d_ws;              // 16 MB
  unsigned short* wb = xb + (size_t)B_DIM * F_DIM;         // 1664 rows = 6.8 MB
  float* sigma = (float*)(wb + (size_t)N_PAD * F_DIM);     // 100x256 f32 (+4 pad rows read-only)

  int nx8 = B_DIM * F_DIM / 8;       // 1048576
  int nw8 = N_DIM * F_DIM / 8;       // 409600
  int npad8 = (N_PAD - N_DIM) * F_DIM / 8;  // 16384
  int nconv = nx8 + nw8 + npad8;
  int grid = C_DIM + (nconv + 255) / 256;   // gram blocks first, then converts
  cvt_gram_kernel<<<grid, 256, 0, stream>>>(x, w, xb, wb, sigma, nx8, nw8, npad8);
  gemm_caps_kernel<<<(B_DIM / 128) * (N_PAD / 128), 256, 0, stream>>>(xb, wb, sigma, out);
}